// Round 4
// baseline (48.260 us; speedup 1.0000x reference)
//
#include <hip/hip_runtime.h>
#include <cstdint>

// MultiboxLoss: B=128, P=8732, C=21
//   out[0] = smooth_ex_loss_sum(pos) / n_pos_total
//   out[1] = CE_sum(pos | mined_neg) / n_pos_total
// Hot path: 3*num_pos >= #negatives -> mined set = ALL priors (decided per row
// at runtime; general top-k fallback kept, fused into k_tail cold path).
// R4: TILE=128/TPB=128 -> LDS 21.5KB/block -> 7 blocks/CU (was 3 at 43KB),
// ~73KB/CU of DMA in flight via TLP; tail kernels fused into one 1-block
// k_tail (5 dispatches -> 3). R3 was 39us total, k_main ~27us vs 15us floor.

#define B_ 128
#define P_ 8732
#define C_ 21
constexpr int TPB = 128;
constexpr int TILE = 128;                    // priors per tile
constexpr int TPROW = 69;                    // tiles per batch row (68 full + 28)
constexpr int TAILCNT = P_ - (TPROW - 1) * TILE;  // 28
constexpr int NTILES = B_ * TPROW;           // 8832
constexpr int TPBLK = 4;                     // tiles per block
constexpr int GRID = NTILES / TPBLK;         // 2208
constexpr int TILE_F = TILE * C_;            // 2688 floats = 10752 B
constexpr int NCHUNK = 11;                   // ceil(10752/1024)

typedef const __attribute__((address_space(1))) uint32_t* gas_u32p;
typedef __attribute__((address_space(3))) uint32_t* las_u32p;

__device__ __forceinline__ float waveSumF(float v) {
#pragma unroll
  for (int o = 32; o; o >>= 1) v += __shfl_down(v, o);
  return v;
}
__device__ __forceinline__ int waveSumI(int v) {
#pragma unroll
  for (int o = 32; o; o >>= 1) v += __shfl_down(v, o);
  return v;
}
__device__ __forceinline__ double waveSumD(double v) {
#pragma unroll
  for (int o = 32; o; o >>= 1) v += __shfl_down(v, o);
  return v;
}

// stage one tile (tilebytes <= 10752) into LDS: 1024B chunks, 2 waves
// round-robin; per-lane exec mask handles the partial last chunk (no OOB
// global reads, no LDS overrun). LDS dest is wave-uniform base (+lane*16 HW).
__device__ __forceinline__ void stage_tile(const float* __restrict__ src,
                                           float* dst, int tilebytes,
                                           int wid, int lane) {
  const char* base = (const char*)src;
  for (int j = wid; j < NCHUNK; j += 2) {
    const int off = (j << 10) + (lane << 4);
    if (off < tilebytes)
      __builtin_amdgcn_global_load_lds((gas_u32p)(base + off),
                                       (las_u32p)(dst + (j << 8)), 16, 0, 0);
  }
}

// ---------------- main streaming kernel ----------------
__global__ __launch_bounds__(TPB) void k_main(
    const float* __restrict__ conf, const float* __restrict__ pred,
    const int* __restrict__ labels, const float* __restrict__ gt,
    float2* __restrict__ part, float* __restrict__ ceneg, int* __restrict__ npos) {
  __shared__ __align__(16) float tile[2][TILE_F];  // 21504 B double buffer
  const int tid = threadIdx.x;
  const int wid = tid >> 6, lane = tid & 63;
  const int tau0 = blockIdx.x * TPBLK;
  const int b_first = tau0 / TPROW;
  const float4* pred4 = (const float4*)pred;
  const float4* gt4 = (const float4*)gt;

  // ---- prologue: stage tile0 + register prefetch for tile0
  {
    const int b = tau0 / TPROW, x = tau0 - b * TPROW;
    const int tb = ((x == TPROW - 1) ? TAILCNT : TILE) * (C_ * 4);
    stage_tile(conf + ((size_t)b * P_ + (size_t)x * TILE) * C_, tile[0], tb, wid, lane);
  }
  int lab_r;
  float4 pr_r, gt_r;
  {
    const int b = tau0 / TPROW, x = tau0 - b * TPROW;
    size_t gp = (size_t)b * P_ + (size_t)x * TILE + tid;
    if (gp > (size_t)B_ * P_ - 1) gp = (size_t)B_ * P_ - 1;
    lab_r = labels[gp];
    pr_r = pred4[gp];
    gt_r = gt4[gp];
  }
  __syncthreads();  // drains vmcnt(0): tile0 + prefetch complete

  float sm_acc = 0.f, cp_acc = 0.f, cn0 = 0.f, cn1 = 0.f;
  int np0 = 0, np1 = 0;

#pragma unroll
  for (int k = 0; k < TPBLK; ++k) {
    const int tau = tau0 + k;
    const int cur = k & 1;

    // ---- issue next tile stage + next register prefetch
    int lab_n = 0;
    float4 pr_n = make_float4(0, 0, 0, 0), gt_n = pr_n;
    if (k + 1 < TPBLK) {
      const int tn = tau + 1;
      const int bn = tn / TPROW, xn = tn - bn * TPROW;
      const int tb = ((xn == TPROW - 1) ? TAILCNT : TILE) * (C_ * 4);
      stage_tile(conf + ((size_t)bn * P_ + (size_t)xn * TILE) * C_, tile[cur ^ 1], tb, wid, lane);
      size_t gp = (size_t)bn * P_ + (size_t)xn * TILE + tid;
      if (gp > (size_t)B_ * P_ - 1) gp = (size_t)B_ * P_ - 1;
      lab_n = labels[gp];
      pr_n = pred4[gp];
      gt_n = gt4[gp];
    }

    // ---- compute tile tau from tile[cur] (staged+drained last iteration)
    const int b = tau / TPROW, x = tau - b * TPROW;
    const int cnt = (x == TPROW - 1) ? TAILCNT : TILE;
    if (tid < cnt) {
      const float* row = &tile[cur][tid * C_];
      float m = row[0];
#pragma unroll
      for (int c = 1; c < C_; ++c) m = fmaxf(m, row[c]);
      float s = 0.f;
#pragma unroll
      for (int c = 0; c < C_; ++c) s += __expf(row[c] - m);
      const float lse = m + __logf(s);
      const float ce = lse - row[lab_r];
      float ce_neg = 0.f;
      int np = 0;
      if (lab_r > 0) {
        np = 1;
        cp_acc += ce;
        // smooth-ex loss, BETA=1 ALPHA=2: a = 1/(1-e^-2), c = a - 1.5
        const float A = 1.1565176427496657f;
        const float Cc = -0.3434823572503343f;
        float d;
        d = fabsf(pr_r.x - gt_r.x); sm_acc += (d < 1.f) ? A * (d + (__expf(-2.f * d) - 1.f) * 0.5f) : d + Cc;
        d = fabsf(pr_r.y - gt_r.y); sm_acc += (d < 1.f) ? A * (d + (__expf(-2.f * d) - 1.f) * 0.5f) : d + Cc;
        d = fabsf(pr_r.z - gt_r.z); sm_acc += (d < 1.f) ? A * (d + (__expf(-2.f * d) - 1.f) * 0.5f) : d + Cc;
        d = fabsf(pr_r.w - gt_r.w); sm_acc += (d < 1.f) ? A * (d + (__expf(-2.f * d) - 1.f) * 0.5f) : d + Cc;
      } else {
        ce_neg = ce;
      }
      if (b == b_first) { cn0 += ce_neg; np0 += np; }
      else             { cn1 += ce_neg; np1 += np; }
    }

    __syncthreads();  // vmcnt(0)+barrier: next tile staged, buffer reusable
    lab_r = lab_n; pr_r = pr_n; gt_r = gt_n;
  }

  // ---- single block-level reduction tail (2 waves)
  float sm = waveSumF(sm_acc), cp = waveSumF(cp_acc);
  float c0 = waveSumF(cn0), c1 = waveSumF(cn1);
  int n0 = waveSumI(np0), n1 = waveSumI(np1);
  float* red = tile[0];  // reuse LDS (post-barrier, no DMA in flight)
  int* redi = (int*)red;
  if (lane == 0) {
    red[wid] = sm; red[2 + wid] = cp; red[4 + wid] = c0; red[6 + wid] = c1;
    redi[8 + wid] = n0; redi[10 + wid] = n1;
  }
  __syncthreads();
  if (tid == 0) {
    float SM = red[0] + red[1], CP = red[2] + red[3];
    float C0 = red[4] + red[5], C1 = red[6] + red[7];
    int N0 = redi[8] + redi[9], N1 = redi[10] + redi[11];
    part[blockIdx.x] = make_float2(SM, CP);  // private slot, no atomic
    atomicAdd(&ceneg[b_first], C0);
    atomicAdd(&npos[b_first], N0);
    const int b_last = (tau0 + TPBLK - 1) / TPROW;
    if (b_last != b_first) {
      atomicAdd(&ceneg[b_last], C1);
      atomicAdd(&npos[b_last], N1);
    }
  }
}

// ---------------- fused tail: reduce + decide + (cold) top-k + finalize ----------------
__device__ __forceinline__ unsigned keyCE(const float* __restrict__ conf,
                                          const int* __restrict__ labels,
                                          int b, int p, float& ce) {
  const float* row = conf + ((size_t)b * P_ + p) * C_;
  float m = row[0];
  for (int c = 1; c < C_; ++c) m = fmaxf(m, row[c]);
  float s = 0.f;
  for (int c = 0; c < C_; ++c) s += __expf(row[c] - m);
  const float lse = m + __logf(s);
  const int lab = labels[(size_t)b * P_ + p];
  ce = lse - row[lab];
  if (lab > 0) return 0u;  // positives excluded
  unsigned u = __float_as_uint(lse - row[0]);  // bg_loss -> order-preserving key
  u = (u & 0x80000000u) ? ~u : (u | 0x80000000u);
  return u ? u : 1u;
}

__global__ __launch_bounds__(256) void k_tail(
    const float2* __restrict__ part, const float* __restrict__ ceneg,
    const int* __restrict__ npos, const float* __restrict__ conf,
    const int* __restrict__ labels, float* __restrict__ out) {
  const int tid = threadIdx.x;
  const int wid = tid >> 6, lane = tid & 63;
  __shared__ double sd0[4], sd1[4], sd2[4];
  __shared__ int si[4];
  __shared__ int s_flag[B_];
  __shared__ double s_extra;
  __shared__ int icnt[4];
  __shared__ float fsum[4];

  // phase 1: reduce GRID float2 partials
  double sm = 0.0, cp = 0.0;
  for (int i = tid; i < GRID; i += 256) {
    const float2 v = part[i];
    sm += (double)v.x;
    cp += (double)v.y;
  }
  sm = waveSumD(sm);
  cp = waveSumD(cp);
  if (lane == 0) { sd0[wid] = sm; sd1[wid] = cp; }

  // phase 2: per-row decision
  double cn = 0.0;
  int n = 0;
  if (tid < B_) {
    const int np = npos[tid];
    const int fl = (3 * np < P_ - np) ? 1 : 0;  // hot: all negs mined -> fl=0
    s_flag[tid] = fl;
    if (!fl) cn = (double)ceneg[tid];
    n = np;
  }
  cn = waveSumD(cn);
  n = waveSumI(n);
  if (lane == 0) { sd2[wid] = cn; si[wid] = n; }
  if (tid == 0) s_extra = 0.0;
  __syncthreads();

  // phase 3: general top-k fallback, cold path (never taken for this data)
  for (int b = 0; b < B_; ++b) {
    if (!s_flag[b]) continue;  // uniform branch (LDS)
    const int need = 3 * npos[b];
    unsigned long long lo = 1, hi = 0xFFFFFFFFull, ans = 1;
    while (lo <= hi) {
      const unsigned long long mid = lo + ((hi - lo) >> 1);
      int c = 0;
      float dummy;
      for (int p = tid; p < P_; p += 256)
        if ((unsigned long long)keyCE(conf, labels, b, p, dummy) >= mid) c++;
      c = waveSumI(c);
      if (lane == 0) icnt[wid] = c;
      __syncthreads();
      const int tot = icnt[0] + icnt[1] + icnt[2] + icnt[3];
      if (tot >= need) { ans = mid; lo = mid + 1; } else { hi = mid - 1; }
      __syncthreads();
    }
    int cgt = 0;
    float sgt = 0.f;
    for (int p = tid; p < P_; p += 256) {
      float ce;
      const unsigned long long k = keyCE(conf, labels, b, p, ce);
      if (k > ans) { cgt++; sgt += ce; }
    }
    cgt = waveSumI(cgt);
    sgt = waveSumF(sgt);
    if (lane == 0) { icnt[wid] = cgt; fsum[wid] = sgt; }
    __syncthreads();
    if (tid == 0) {
      const int gtot = icnt[0] + icnt[1] + icnt[2] + icnt[3];
      double s = (double)(fsum[0] + fsum[1] + fsum[2] + fsum[3]);
      int r = need - gtot;
      int taken = 0;
      for (int p = 0; p < P_ && taken < r; ++p) {  // stable tie-break by index
        float ce;
        if (keyCE(conf, labels, b, p, ce) == ans) { s += ce; taken++; }
      }
      s_extra += s;
    }
    __syncthreads();
  }

  // phase 4: finalize
  if (tid == 0) {
    const double G0 = sd0[0] + sd0[1] + sd0[2] + sd0[3];
    const double G1 = sd1[0] + sd1[1] + sd1[2] + sd1[3];
    const double G2 = sd2[0] + sd2[1] + sd2[2] + sd2[3] + s_extra;
    const double N = (double)(si[0] + si[1] + si[2] + si[3]);
    out[0] = (float)(G0 / N);
    out[1] = (float)((G1 + G2) / N);
  }
}

extern "C" void kernel_launch(void* const* d_in, const int* in_sizes, int n_in,
                              void* d_out, int out_size, void* d_ws, size_t ws_size,
                              hipStream_t stream) {
  const float* conf = (const float*)d_in[0];
  const float* pred = (const float*)d_in[1];
  const int* labels = (const int*)d_in[2];
  const float* gt = (const float*)d_in[3];
  float* out = (float*)d_out;

  // ws layout
  float* ceneg = (float*)d_ws;           // [B_]   (atomics, needs zero)
  int* npos = (int*)(ceneg + B_);        // [B_]   (atomics, needs zero)
  float2* part = (float2*)(npos + B_);   // [GRID] (fully written by k_main)
  hipMemsetAsync(d_ws, 0, B_ * (sizeof(float) + sizeof(int)), stream);

  hipLaunchKernelGGL(k_main, dim3(GRID), dim3(TPB), 0, stream,
                     conf, pred, labels, gt, part, ceneg, npos);
  hipLaunchKernelGGL(k_tail, dim3(1), dim3(256), 0, stream,
                     part, ceneg, npos, conf, labels, out);
}

// Round 5
// 39.748 us; speedup vs baseline: 1.2141x; 1.2141x over previous
//
#include <hip/hip_runtime.h>
#include <cstdint>

// MultiboxLoss: B=128, P=8732, C=21
//   out[0] = smooth_ex_loss_sum(pos) / n_pos_total
//   out[1] = CE_sum(pos | mined_neg) / n_pos_total
// Hot path: 3*num_pos >= #negatives -> mined set = ALL priors (decided per row
// at runtime; general top-k fallback kept in k_tail cold path).
// R5: barrier-free register streaming. R2-R4 (LDS staging + __syncthreads
// vmcnt(0) drain per tile) were stuck at 27-40us while ALL roofs (HBM 21us,
// L3-warm ~10us, VALU ~6us) are lower; replay passes showed ~55us at ~zero
// HBM traffic -> structure-bound, waits correlated by barriers (VALUBusy 12%).
// Now: no LDS, no barriers in hot loop, no atomics; one row per block,
// 16 blocks/row (grid 2048 = 8 blocks/CU), per-thread MLP of ~9 loads.

#define B_ 128
#define P_ 8732
#define C_ 21
constexpr int BPR = 16;            // blocks per row
constexpr int TPB = 256;
constexpr int GRID = B_ * BPR;     // 2048
constexpr int STRIDE = BPR * TPB;  // 4096 threads per row

// 4B-aligned float4: conf rows are 84B apart, only dword-aligned.
typedef float f32x4u __attribute__((ext_vector_type(4), aligned(4)));

__device__ __forceinline__ float waveSumF(float v) {
#pragma unroll
  for (int o = 32; o; o >>= 1) v += __shfl_down(v, o);
  return v;
}
__device__ __forceinline__ int waveSumI(int v) {
#pragma unroll
  for (int o = 32; o; o >>= 1) v += __shfl_down(v, o);
  return v;
}
__device__ __forceinline__ double waveSumD(double v) {
#pragma unroll
  for (int o = 32; o; o >>= 1) v += __shfl_down(v, o);
  return v;
}

// ---------------- main streaming kernel: no LDS, no barriers, no atomics ----------------
__global__ __launch_bounds__(TPB) void k_main(
    const float* __restrict__ conf, const float* __restrict__ pred,
    const int* __restrict__ labels, const float* __restrict__ gt,
    float4* __restrict__ part) {
  const int tid = threadIdx.x;
  const int row = blockIdx.x >> 4;  // BPR = 16
  const int sub = blockIdx.x & 15;
  const int t0 = sub * TPB + tid;
  const size_t rowBase = (size_t)row * P_;
  const float4* pred4 = (const float4*)pred;
  const float4* gt4 = (const float4*)gt;

  float sm = 0.f, cp = 0.f, cn = 0.f;
  int np = 0;

  for (int p = t0; p < P_; p += STRIDE) {
    const size_t gp = rowBase + p;
    const float* r = conf + gp * C_;
    // 21-float conf row into registers: 5 x dwordx4 (4B-aligned) + 1 dword.
    // A wave's 6 loads re-touch the same ~84 contiguous cache lines -> L1-hot.
    float f[C_];
    {
      const f32x4u* r4 = (const f32x4u*)r;
      const f32x4u v0 = r4[0], v1 = r4[1], v2 = r4[2], v3 = r4[3], v4 = r4[4];
      f[0] = v0.x; f[1] = v0.y; f[2] = v0.z; f[3] = v0.w;
      f[4] = v1.x; f[5] = v1.y; f[6] = v1.z; f[7] = v1.w;
      f[8] = v2.x; f[9] = v2.y; f[10] = v2.z; f[11] = v2.w;
      f[12] = v3.x; f[13] = v3.y; f[14] = v3.z; f[15] = v3.w;
      f[16] = v4.x; f[17] = v4.y; f[18] = v4.z; f[19] = v4.w;
      f[20] = r[20];
    }
    const int lab = labels[gp];
    const float4 pr = pred4[gp];
    const float4 gv = gt4[gp];

    float m = f[0];
#pragma unroll
    for (int c = 1; c < C_; ++c) m = fmaxf(m, f[c]);
    float s = 0.f;
    float xl = f[0];  // f[lab] via cndmask chain (static idx only; rule #20)
#pragma unroll
    for (int c = 0; c < C_; ++c) {
      s += __expf(f[c] - m);
      if (c > 0) xl = (lab == c) ? f[c] : xl;
    }
    const float ce = m + __logf(s) - xl;

    if (lab > 0) {
      np++;
      cp += ce;
      // smooth-ex loss, BETA=1 ALPHA=2: a = 1/(1-e^-2), c = a - 1.5
      const float A = 1.1565176427496657f;
      const float Cc = -0.3434823572503343f;
      float d;
      d = fabsf(pr.x - gv.x); sm += (d < 1.f) ? A * (d + (__expf(-2.f * d) - 1.f) * 0.5f) : d + Cc;
      d = fabsf(pr.y - gv.y); sm += (d < 1.f) ? A * (d + (__expf(-2.f * d) - 1.f) * 0.5f) : d + Cc;
      d = fabsf(pr.z - gv.z); sm += (d < 1.f) ? A * (d + (__expf(-2.f * d) - 1.f) * 0.5f) : d + Cc;
      d = fabsf(pr.w - gv.w); sm += (d < 1.f) ? A * (d + (__expf(-2.f * d) - 1.f) * 0.5f) : d + Cc;
    } else {
      cn += ce;
    }
  }

  // single block reduction -> private float4 slot (block covers ONE row)
  float a0 = waveSumF(sm), a1 = waveSumF(cp), a2 = waveSumF(cn);
  int a3 = waveSumI(np);
  __shared__ float s0[4], s1[4], s2[4];
  __shared__ int s3[4];
  const int wid = tid >> 6, lane = tid & 63;
  if (lane == 0) { s0[wid] = a0; s1[wid] = a1; s2[wid] = a2; s3[wid] = a3; }
  __syncthreads();
  if (tid == 0) {
    part[blockIdx.x] = make_float4(
        s0[0] + s0[1] + s0[2] + s0[3], s1[0] + s1[1] + s1[2] + s1[3],
        s2[0] + s2[1] + s2[2] + s2[3], (float)(s3[0] + s3[1] + s3[2] + s3[3]));
  }
}

// ---------------- fused tail: reduce + decide + (cold) top-k + finalize ----------------
__device__ __forceinline__ unsigned keyCE(const float* __restrict__ conf,
                                          const int* __restrict__ labels,
                                          int b, int p, float& ce) {
  const float* row = conf + ((size_t)b * P_ + p) * C_;
  float m = row[0];
  for (int c = 1; c < C_; ++c) m = fmaxf(m, row[c]);
  float s = 0.f;
  for (int c = 0; c < C_; ++c) s += __expf(row[c] - m);
  const float lse = m + __logf(s);
  const int lab = labels[(size_t)b * P_ + p];
  ce = lse - row[lab];
  if (lab > 0) return 0u;  // positives excluded
  unsigned u = __float_as_uint(lse - row[0]);  // bg_loss -> order-preserving key
  u = (u & 0x80000000u) ? ~u : (u | 0x80000000u);
  return u ? u : 1u;
}

__global__ __launch_bounds__(128) void k_tail(
    const float4* __restrict__ part, const float* __restrict__ conf,
    const int* __restrict__ labels, float* __restrict__ out) {
  const int tid = threadIdx.x;  // 128 threads = 2 waves; thread t owns row t
  const int wid = tid >> 6, lane = tid & 63;
  __shared__ int s_np[B_], s_flag[B_];
  __shared__ double sdA[2], sdB[2], sdC[2];
  __shared__ int siN[2];
  __shared__ double s_extra;
  __shared__ int icnt[2];
  __shared__ float fsum[2];

  // per-row gather over this row's BPR slots (deterministic fixed order)
  double sm = 0.0, cp = 0.0, cnSel = 0.0;
  int npr = 0;
  {
    double cn = 0.0;
#pragma unroll
    for (int i = 0; i < BPR; ++i) {
      const float4 v = part[tid * BPR + i];
      sm += (double)v.x;
      cp += (double)v.y;
      cn += (double)v.z;
      npr += (int)v.w;
    }
    s_np[tid] = npr;
    const int fl = (3 * npr < P_ - npr) ? 1 : 0;  // hot: all negs mined -> 0
    s_flag[tid] = fl;
    if (!fl) cnSel = cn;
  }
  const double t1 = waveSumD(sm), t2 = waveSumD(cp), t3 = waveSumD(cnSel);
  const int t4 = waveSumI(npr);
  if (lane == 0) { sdA[wid] = t1; sdB[wid] = t2; sdC[wid] = t3; siN[wid] = t4; }
  if (tid == 0) s_extra = 0.0;
  __syncthreads();

  // cold path: general top-k fallback (never taken for this data)
  for (int b = 0; b < B_; ++b) {
    if (!s_flag[b]) continue;  // uniform (LDS)
    const int need = 3 * s_np[b];
    unsigned long long lo = 1, hi = 0xFFFFFFFFull, ans = 1;
    while (lo <= hi) {
      const unsigned long long mid = lo + ((hi - lo) >> 1);
      int c = 0;
      float dummy;
      for (int p = tid; p < P_; p += 128)
        if ((unsigned long long)keyCE(conf, labels, b, p, dummy) >= mid) c++;
      c = waveSumI(c);
      if (lane == 0) icnt[wid] = c;
      __syncthreads();
      const int tot = icnt[0] + icnt[1];
      if (tot >= need) { ans = mid; lo = mid + 1; } else { hi = mid - 1; }
      __syncthreads();
    }
    int cgt = 0;
    float sgt = 0.f;
    for (int p = tid; p < P_; p += 128) {
      float ce;
      const unsigned long long k = keyCE(conf, labels, b, p, ce);
      if (k > ans) { cgt++; sgt += ce; }
    }
    cgt = waveSumI(cgt);
    sgt = waveSumF(sgt);
    if (lane == 0) { icnt[wid] = cgt; fsum[wid] = sgt; }
    __syncthreads();
    if (tid == 0) {
      const int gtot = icnt[0] + icnt[1];
      double s = (double)(fsum[0] + fsum[1]);
      int rm = need - gtot;
      int taken = 0;
      for (int p = 0; p < P_ && taken < rm; ++p) {  // stable tie-break by index
        float ce;
        if (keyCE(conf, labels, b, p, ce) == ans) { s += ce; taken++; }
      }
      s_extra += s;
    }
    __syncthreads();
  }

  // finalize
  if (tid == 0) {
    const double G0 = sdA[0] + sdA[1];
    const double G1 = sdB[0] + sdB[1];
    const double G2 = sdC[0] + sdC[1] + s_extra;
    const double N = (double)(siN[0] + siN[1]);
    out[0] = (float)(G0 / N);
    out[1] = (float)((G1 + G2) / N);
  }
}

extern "C" void kernel_launch(void* const* d_in, const int* in_sizes, int n_in,
                              void* d_out, int out_size, void* d_ws, size_t ws_size,
                              hipStream_t stream) {
  const float* conf = (const float*)d_in[0];
  const float* pred = (const float*)d_in[1];
  const int* labels = (const int*)d_in[2];
  const float* gt = (const float*)d_in[3];
  float* out = (float*)d_out;

  // ws: part[GRID] float4, fully overwritten by k_main each call (no memset).
  float4* part = (float4*)d_ws;

  hipLaunchKernelGGL(k_main, dim3(GRID), dim3(TPB), 0, stream,
                     conf, pred, labels, gt, part);
  hipLaunchKernelGGL(k_tail, dim3(1), dim3(128), 0, stream,
                     part, conf, labels, out);
}

// Round 6
// 39.230 us; speedup vs baseline: 1.2302x; 1.0132x over previous
//
#include <hip/hip_runtime.h>
#include <cstdint>

// MultiboxLoss: B=128, P=8732, C=21
//   out[0] = smooth_ex_loss_sum(pos) / n_pos_total
//   out[1] = CE_sum(pos | mined_neg) / n_pos_total
// Hot path: 3*num_pos >= #negatives -> mined set = ALL priors (decided per row
// at runtime; general top-k fallback kept in k_tail cold path).
// R6: R5 showed VGPR_Count=24 -> compiler spilled the f[21] row to scratch and
// SERIALIZED the 9 loads/prior (Little's law: ~0.3 loads in flight -> 1.19TB/s
// measured; warm==cold duration -> latency-chain-bound). Fix: no local arrays
// (named f32x4u regs, hand-unrolled), 3 priors/thread with ALL ~27 loads
// issued up front (252B/lane payload), __launch_bounds__(256,2) for VGPR
// headroom, branchless accumulation. No LDS/barriers/atomics in hot path.

#define B_ 128
#define P_ 8732
#define C_ 21
constexpr int BPR = 16;            // sub-blocks per row
constexpr int TPB = 256;
constexpr int GRID = B_ * BPR;     // 2048
constexpr int TPR = BPR * TPB;     // 4096 threads per row
// priors per thread = 3: p0 in [0,4096), p1 = p0+4096 (<8732 always),
// p2 = p0+8192 (active iff p0 < 540)

// 4B-aligned float4: conf rows are 84B apart, only dword-aligned.
typedef float f32x4u __attribute__((ext_vector_type(4), aligned(4)));

__device__ __forceinline__ float waveSumF(float v) {
#pragma unroll
  for (int o = 32; o; o >>= 1) v += __shfl_down(v, o);
  return v;
}
__device__ __forceinline__ int waveSumI(int v) {
#pragma unroll
  for (int o = 32; o; o >>= 1) v += __shfl_down(v, o);
  return v;
}
__device__ __forceinline__ double waveSumD(double v) {
#pragma unroll
  for (int o = 32; o; o >>= 1) v += __shfl_down(v, o);
  return v;
}

#define SMEX(d) (((d) < 1.f) ? (1.1565176427496657f * ((d) + (__expf(-2.f * (d)) - 1.f) * 0.5f)) \
                             : ((d) - 0.3434823572503343f))

// one prior, fully unrolled on named registers (no local arrays -> no scratch)
__device__ __forceinline__ void doPrior(
    f32x4u v0, f32x4u v1, f32x4u v2, f32x4u v3, f32x4u v4, float t20,
    int lab, float4 pr, float4 gv, bool act,
    float& sm, float& cp, float& cn, int& np) {
  float m = fmaxf(fmaxf(fmaxf(v0.x, v0.y), fmaxf(v0.z, v0.w)),
                  fmaxf(fmaxf(v1.x, v1.y), fmaxf(v1.z, v1.w)));
  m = fmaxf(m, fmaxf(fmaxf(v2.x, v2.y), fmaxf(v2.z, v2.w)));
  m = fmaxf(m, fmaxf(fmaxf(v3.x, v3.y), fmaxf(v3.z, v3.w)));
  m = fmaxf(m, fmaxf(fmaxf(v4.x, v4.y), fmaxf(v4.z, v4.w)));
  m = fmaxf(m, t20);
  float s = __expf(v0.x - m) + __expf(v0.y - m) + __expf(v0.z - m) + __expf(v0.w - m);
  s += __expf(v1.x - m) + __expf(v1.y - m) + __expf(v1.z - m) + __expf(v1.w - m);
  s += __expf(v2.x - m) + __expf(v2.y - m) + __expf(v2.z - m) + __expf(v2.w - m);
  s += __expf(v3.x - m) + __expf(v3.y - m) + __expf(v3.z - m) + __expf(v3.w - m);
  s += __expf(v4.x - m) + __expf(v4.y - m) + __expf(v4.z - m) + __expf(v4.w - m);
  s += __expf(t20 - m);
  float xl = v0.x;  // f[lab] via static cndmask chain
  xl = (lab == 1) ? v0.y : xl;  xl = (lab == 2) ? v0.z : xl;
  xl = (lab == 3) ? v0.w : xl;  xl = (lab == 4) ? v1.x : xl;
  xl = (lab == 5) ? v1.y : xl;  xl = (lab == 6) ? v1.z : xl;
  xl = (lab == 7) ? v1.w : xl;  xl = (lab == 8) ? v2.x : xl;
  xl = (lab == 9) ? v2.y : xl;  xl = (lab == 10) ? v2.z : xl;
  xl = (lab == 11) ? v2.w : xl; xl = (lab == 12) ? v3.x : xl;
  xl = (lab == 13) ? v3.y : xl; xl = (lab == 14) ? v3.z : xl;
  xl = (lab == 15) ? v3.w : xl; xl = (lab == 16) ? v4.x : xl;
  xl = (lab == 17) ? v4.y : xl; xl = (lab == 18) ? v4.z : xl;
  xl = (lab == 19) ? v4.w : xl; xl = (lab == 20) ? t20 : xl;
  const float ce = m + __logf(s) - xl;

  float d, smx;
  d = fabsf(pr.x - gv.x); smx = SMEX(d);
  d = fabsf(pr.y - gv.y); smx += SMEX(d);
  d = fabsf(pr.z - gv.z); smx += SMEX(d);
  d = fabsf(pr.w - gv.w); smx += SMEX(d);

  const bool pos = act && (lab > 0);
  sm += pos ? smx : 0.f;
  cp += pos ? ce : 0.f;
  cn += (act && lab == 0) ? ce : 0.f;
  np += pos ? 1 : 0;
}

// ---------------- main kernel: no LDS staging, no barriers, no atomics ----------------
__global__ __launch_bounds__(TPB, 2) void k_main(
    const float* __restrict__ conf, const float* __restrict__ pred,
    const int* __restrict__ labels, const float* __restrict__ gt,
    float4* __restrict__ part) {
  const int tid = threadIdx.x;
  const int row = blockIdx.x >> 4;  // BPR = 16
  const int sub = blockIdx.x & 15;
  const int p0 = sub * TPB + tid;   // [0, 4096)
  const int p1 = p0 + TPR;          // [4096, 8192) < P_ always
  const int p2 = p0 + 2 * TPR;
  const bool act2 = p2 < P_;        // first 540 threads only
  const int p2c = act2 ? p2 : p0;   // clamp: safe read, contribution masked
  const size_t rb = (size_t)row * P_;
  const float4* pred4 = (const float4*)pred;
  const float4* gt4 = (const float4*)gt;

  // ---- issue ALL loads up front (27 independent loads, one latency) ----
  const f32x4u* q0 = (const f32x4u*)(conf + (rb + p0) * C_);
  const f32x4u* q1 = (const f32x4u*)(conf + (rb + p1) * C_);
  const f32x4u* q2 = (const f32x4u*)(conf + (rb + p2c) * C_);
  const f32x4u a0 = q0[0], a1 = q0[1], a2 = q0[2], a3 = q0[3], a4 = q0[4];
  const f32x4u b0 = q1[0], b1 = q1[1], b2 = q1[2], b3 = q1[3], b4 = q1[4];
  const f32x4u c0 = q2[0], c1 = q2[1], c2 = q2[2], c3 = q2[3], c4 = q2[4];
  const float a5 = ((const float*)q0)[20];
  const float b5 = ((const float*)q1)[20];
  const float c5 = ((const float*)q2)[20];
  const int la = labels[rb + p0], lb = labels[rb + p1], lc = labels[rb + p2c];
  const float4 pra = pred4[rb + p0], prb = pred4[rb + p1], prc = pred4[rb + p2c];
  const float4 gva = gt4[rb + p0], gvb = gt4[rb + p1], gvc = gt4[rb + p2c];

  // ---- pure VALU from here ----
  float sm = 0.f, cp = 0.f, cn = 0.f;
  int np = 0;
  doPrior(a0, a1, a2, a3, a4, a5, la, pra, gva, true, sm, cp, cn, np);
  doPrior(b0, b1, b2, b3, b4, b5, lb, prb, gvb, true, sm, cp, cn, np);
  doPrior(c0, c1, c2, c3, c4, c5, lc, prc, gvc, act2, sm, cp, cn, np);

  // single block reduction -> private float4 slot (block covers ONE row)
  float r0 = waveSumF(sm), r1 = waveSumF(cp), r2 = waveSumF(cn);
  int r3 = waveSumI(np);
  __shared__ float s0[4], s1[4], s2[4];
  __shared__ int s3[4];
  const int wid = tid >> 6, lane = tid & 63;
  if (lane == 0) { s0[wid] = r0; s1[wid] = r1; s2[wid] = r2; s3[wid] = r3; }
  __syncthreads();
  if (tid == 0) {
    part[blockIdx.x] = make_float4(
        s0[0] + s0[1] + s0[2] + s0[3], s1[0] + s1[1] + s1[2] + s1[3],
        s2[0] + s2[1] + s2[2] + s2[3], (float)(s3[0] + s3[1] + s3[2] + s3[3]));
  }
}

// ---------------- fused tail: reduce + decide + (cold) top-k + finalize ----------------
__device__ __forceinline__ unsigned keyCE(const float* __restrict__ conf,
                                          const int* __restrict__ labels,
                                          int b, int p, float& ce) {
  const float* row = conf + ((size_t)b * P_ + p) * C_;
  float m = row[0];
  for (int c = 1; c < C_; ++c) m = fmaxf(m, row[c]);
  float s = 0.f;
  for (int c = 0; c < C_; ++c) s += __expf(row[c] - m);
  const float lse = m + __logf(s);
  const int lab = labels[(size_t)b * P_ + p];
  ce = lse - row[lab];
  if (lab > 0) return 0u;  // positives excluded
  unsigned u = __float_as_uint(lse - row[0]);  // bg_loss -> order-preserving key
  u = (u & 0x80000000u) ? ~u : (u | 0x80000000u);
  return u ? u : 1u;
}

__global__ __launch_bounds__(128) void k_tail(
    const float4* __restrict__ part, const float* __restrict__ conf,
    const int* __restrict__ labels, float* __restrict__ out) {
  const int tid = threadIdx.x;  // 128 threads = 2 waves; thread t owns row t
  const int wid = tid >> 6, lane = tid & 63;
  __shared__ int s_np[B_], s_flag[B_];
  __shared__ double sdA[2], sdB[2], sdC[2];
  __shared__ int siN[2];
  __shared__ double s_extra;
  __shared__ int icnt[2];
  __shared__ float fsum[2];

  // per-row gather over this row's BPR slots (deterministic fixed order)
  double sm = 0.0, cp = 0.0, cnSel = 0.0;
  int npr = 0;
  {
    double cn = 0.0;
#pragma unroll
    for (int i = 0; i < BPR; ++i) {
      const float4 v = part[tid * BPR + i];
      sm += (double)v.x;
      cp += (double)v.y;
      cn += (double)v.z;
      npr += (int)v.w;
    }
    s_np[tid] = npr;
    const int fl = (3 * npr < P_ - npr) ? 1 : 0;  // hot: all negs mined -> 0
    s_flag[tid] = fl;
    if (!fl) cnSel = cn;
  }
  const double t1 = waveSumD(sm), t2 = waveSumD(cp), t3 = waveSumD(cnSel);
  const int t4 = waveSumI(npr);
  if (lane == 0) { sdA[wid] = t1; sdB[wid] = t2; sdC[wid] = t3; siN[wid] = t4; }
  if (tid == 0) s_extra = 0.0;
  __syncthreads();

  // cold path: general top-k fallback (never taken for this data)
  for (int b = 0; b < B_; ++b) {
    if (!s_flag[b]) continue;  // uniform (LDS)
    const int need = 3 * s_np[b];
    unsigned long long lo = 1, hi = 0xFFFFFFFFull, ans = 1;
    while (lo <= hi) {
      const unsigned long long mid = lo + ((hi - lo) >> 1);
      int c = 0;
      float dummy;
      for (int p = tid; p < P_; p += 128)
        if ((unsigned long long)keyCE(conf, labels, b, p, dummy) >= mid) c++;
      c = waveSumI(c);
      if (lane == 0) icnt[wid] = c;
      __syncthreads();
      const int tot = icnt[0] + icnt[1];
      if (tot >= need) { ans = mid; lo = mid + 1; } else { hi = mid - 1; }
      __syncthreads();
    }
    int cgt = 0;
    float sgt = 0.f;
    for (int p = tid; p < P_; p += 128) {
      float ce;
      const unsigned long long k = keyCE(conf, labels, b, p, ce);
      if (k > ans) { cgt++; sgt += ce; }
    }
    cgt = waveSumI(cgt);
    sgt = waveSumF(sgt);
    if (lane == 0) { icnt[wid] = cgt; fsum[wid] = sgt; }
    __syncthreads();
    if (tid == 0) {
      const int gtot = icnt[0] + icnt[1];
      double s = (double)(fsum[0] + fsum[1]);
      int rm = need - gtot;
      int taken = 0;
      for (int p = 0; p < P_ && taken < rm; ++p) {  // stable tie-break by index
        float ce;
        if (keyCE(conf, labels, b, p, ce) == ans) { s += ce; taken++; }
      }
      s_extra += s;
    }
    __syncthreads();
  }

  // finalize
  if (tid == 0) {
    const double G0 = sdA[0] + sdA[1];
    const double G1 = sdB[0] + sdB[1];
    const double G2 = sdC[0] + sdC[1] + s_extra;
    const double N = (double)(siN[0] + siN[1]);
    out[0] = (float)(G0 / N);
    out[1] = (float)((G1 + G2) / N);
  }
}

extern "C" void kernel_launch(void* const* d_in, const int* in_sizes, int n_in,
                              void* d_out, int out_size, void* d_ws, size_t ws_size,
                              hipStream_t stream) {
  const float* conf = (const float*)d_in[0];
  const float* pred = (const float*)d_in[1];
  const int* labels = (const int*)d_in[2];
  const float* gt = (const float*)d_in[3];
  float* out = (float*)d_out;

  // ws: part[GRID] float4, fully overwritten by k_main each call (no memset).
  float4* part = (float4*)d_ws;

  hipLaunchKernelGGL(k_main, dim3(GRID), dim3(TPB), 0, stream,
                     conf, pred, labels, gt, part);
  hipLaunchKernelGGL(k_tail, dim3(1), dim3(128), 0, stream,
                     part, conf, labels, out);
}